// Round 3
// baseline (127.876 us; speedup 1.0000x reference)
//
#include <hip/hip_runtime.h>

// Problem constants
#define NB 4      // batch
#define NI 160    // input spatial size (all 3 dims)
#define NO 43     // output spatial size: ceil(160/4)+3
#define NC 3      // channels
#define KS 7      // gaussian kernel size per axis
#define KPAD 3    // (KS-1)/2
#define MT 16     // stored taps per composite-weight row (true max = 14)
#define CH 8      // i2 rows per chunk in fused fallback pass A

#define ROWF (NI * NC)           // 480 floats per innermost row
#define ROW4 (ROWF / 4)          // 120 float4s
#define COLS (NO * NC)           // 129
#define SLICE (NO * NO * NC)     // 5547

#define A1_ELEMS ((size_t)NB * NI * NO * ROWF)      // 13,209,600  [b][i1][o2][i3c]
#define A2_ELEMS ((size_t)NB * NO * NO * ROWF)      // 3,550,080   [b][o1][o2][i3c]
#define OUT_ELEMS ((size_t)NB * NO * SLICE)         // 954,084

// Workspace layout:
//  0       : wtab[3*43*16] f32   (axis 0 = i1, 1 = i2, 2 = i3)
//  8256    : wstart[3*43] i32
//  9216    : otab[3*43*16] i32   (clamped tap offsets, premultiplied to BYTES:
//                                 axis0 stride 43*480*4, axis1 480*4, axis2 3*4)
//  32768   : A1 (52.8 MB) then A2 (14.2 MB)     [fast path]
//  32768   : S  (14.2 MB)                        [fallback path]

// ---------------------------------------------------------------------------
// Setup: factor 3D gaussian into per-axis marginals, compose with the
// jax.image.resize (antialias=True, 'linear') triangle weights into a banded
// 43x160 matrix per axis (<=14 taps, stored as 16 with zero pad). Also emit
// clamped, stride-premultiplied byte offsets per tap.
// ---------------------------------------------------------------------------
__global__ void k_setup(const float* __restrict__ kern,
                        float* __restrict__ wtab, int* __restrict__ wstart,
                        int* __restrict__ otab) {
    __shared__ float g[3 * KS];
    int t = threadIdx.x;
    if (t < 3 * KS) {
        int ax = t / KS, idx = t % KS;
        float s = 0.f;
        for (int a = 0; a < KS; ++a)
            for (int b = 0; b < KS; ++b) {
                int i0 = (ax == 0) ? idx : a;
                int i1 = (ax == 1) ? idx : ((ax == 0) ? a : b);
                int i2 = (ax == 2) ? idx : b;
                s += kern[(i0 * KS + i1) * KS + i2];
            }
        g[t] = s;
    }
    __syncthreads();

    const float inv_scale = (float)NI / (float)NO;   // 160/43
    const float ksc = inv_scale;                     // kernel_scale (antialias)
    for (int row = t; row < 3 * NO; row += blockDim.x) {
        int ax = row / NO, o = row % NO;
        float sf = ((float)o + 0.5f) * inv_scale - 0.5f;   // half-pixel centers
        int ilo = (int)ceilf(sf - ksc);  if (ilo < 0) ilo = 0;
        int ihi = (int)floorf(sf + ksc); if (ihi > NI - 1) ihi = NI - 1;
        float wsum = 0.f;
        for (int i = ilo; i <= ihi; ++i)
            wsum += fmaxf(0.f, 1.f - fabsf(sf - (float)i) / ksc);
        int jlo = ilo - KPAD; if (jlo < 0) jlo = 0;
        int jhi = ihi + KPAD; if (jhi > NI - 1) jhi = NI - 1;
        wstart[row] = jlo;
        int stride_b = (ax == 0) ? (NO * ROWF * 4) : ((ax == 1) ? (ROWF * 4) : (NC * 4));
        for (int k = 0; k < MT; ++k) {
            int j = jlo + k;
            float cw = 0.f;
            if (j <= jhi) {
                for (int tt = 0; tt < KS; ++tt) {
                    int i = j + KPAD - tt;   // blurred index feeding img[j]
                    if (i >= ilo && i <= ihi) {
                        float w = fmaxf(0.f, 1.f - fabsf(sf - (float)i) / ksc) / wsum;
                        cw += g[ax * KS + tt] * w;
                    }
                }
            }
            wtab[row * MT + k] = cw;
            int jc = (j < NI) ? j : (NI - 1);            // pad taps have w=0
            otab[row * MT + k] = jc * stride_b;
        }
    }
}

// ---------------------------------------------------------------------------
// FAST P1: contract i2 -> o2.  A1[b][i1][o2][i3c]
// Thread = one float4 along (i3,c); 16 taps, each a coalesced dwordx4.
// ---------------------------------------------------------------------------
__global__ __launch_bounds__(256) void k_c2(
        const float* __restrict__ img, const float* __restrict__ wtab,
        const int* __restrict__ otab, float* __restrict__ A1) {
    int idx = blockIdx.x * 256 + threadIdx.x;
    // total = NB*NI*NO*ROW4 = 3,302,400 (exact multiple of 256)
    int col4 = idx % ROW4;
    int o2   = (idx / ROW4) % NO;
    int slab = idx / (ROW4 * NO);          // b*160 + i1
    const char* base = (const char*)(img + (size_t)slab * (NI * ROWF) + col4 * 4);
    const float4* wv = (const float4*)(wtab + (NO + o2) * MT);
    const int4*   ov = (const int4*)(otab + (NO + o2) * MT);
    float4 w0 = wv[0], w1 = wv[1], w2 = wv[2], w3 = wv[3];
    int4   j0 = ov[0], j1 = ov[1], j2 = ov[2], j3 = ov[3];
    float4 a = {0.f, 0.f, 0.f, 0.f};
#define TAP4(J, W) { float4 v = *(const float4*)(base + (size_t)(unsigned)(J)); \
                     a.x += (W) * v.x; a.y += (W) * v.y; a.z += (W) * v.z; a.w += (W) * v.w; }
    TAP4(j0.x, w0.x) TAP4(j0.y, w0.y) TAP4(j0.z, w0.z) TAP4(j0.w, w0.w)
    TAP4(j1.x, w1.x) TAP4(j1.y, w1.y) TAP4(j1.z, w1.z) TAP4(j1.w, w1.w)
    TAP4(j2.x, w2.x) TAP4(j2.y, w2.y) TAP4(j2.z, w2.z) TAP4(j2.w, w2.w)
    TAP4(j3.x, w3.x) TAP4(j3.y, w3.y) TAP4(j3.z, w3.z) TAP4(j3.w, w3.w)
#undef TAP4
    ((float4*)A1)[idx] = a;
}

// ---------------------------------------------------------------------------
// FAST P2: contract i1 -> o1.  A2[b][o1][o2][i3c]
// ---------------------------------------------------------------------------
__global__ __launch_bounds__(256) void k_c1(
        const float* __restrict__ A1, const float* __restrict__ wtab,
        const int* __restrict__ otab, float* __restrict__ A2) {
    size_t tid = (size_t)blockIdx.x * 256 + threadIdx.x;
    if (tid >= (size_t)NB * NO * NO * ROW4) return;
    int idx = (int)tid;
    int col4 = idx % ROW4;
    int o2   = (idx / ROW4) % NO;
    int o1   = (idx / (ROW4 * NO)) % NO;
    int b    = idx / (ROW4 * NO * NO);
    const char* base = (const char*)(A1 + ((size_t)b * NI * NO + o2) * ROWF + col4 * 4);
    const float4* wv = (const float4*)(wtab + o1 * MT);
    const int4*   ov = (const int4*)(otab + o1 * MT);
    float4 w0 = wv[0], w1 = wv[1], w2 = wv[2], w3 = wv[3];
    int4   j0 = ov[0], j1 = ov[1], j2 = ov[2], j3 = ov[3];
    float4 a = {0.f, 0.f, 0.f, 0.f};
#define TAP4(J, W) { float4 v = *(const float4*)(base + (size_t)(unsigned)(J)); \
                     a.x += (W) * v.x; a.y += (W) * v.y; a.z += (W) * v.z; a.w += (W) * v.w; }
    TAP4(j0.x, w0.x) TAP4(j0.y, w0.y) TAP4(j0.z, w0.z) TAP4(j0.w, w0.w)
    TAP4(j1.x, w1.x) TAP4(j1.y, w1.y) TAP4(j1.z, w1.z) TAP4(j1.w, w1.w)
    TAP4(j2.x, w2.x) TAP4(j2.y, w2.y) TAP4(j2.z, w2.z) TAP4(j2.w, w2.w)
    TAP4(j3.x, w3.x) TAP4(j3.y, w3.y) TAP4(j3.z, w3.z) TAP4(j3.w, w3.w)
#undef TAP4
    ((float4*)A2)[idx] = a;
}

// ---------------------------------------------------------------------------
// FAST P3: contract i3 -> o3 (gather, stride 12B, data is L2-hot).
// Thread = one (b,o1,o2,o3), all 3 channels.
// ---------------------------------------------------------------------------
__global__ __launch_bounds__(256) void k_c3(
        const float* __restrict__ A2, const float* __restrict__ wtab,
        const int* __restrict__ otab, float* __restrict__ out) {
    size_t tid = (size_t)blockIdx.x * 256 + threadIdx.x;
    if (tid >= (size_t)NB * NO * NO * NO) return;
    int idx = (int)tid;
    int o3  = idx % NO;
    int row = idx / NO;                    // (b*43+o1)*43+o2
    const char* base = (const char*)(A2 + (size_t)row * ROWF);
    const float4* wv = (const float4*)(wtab + (2 * NO + o3) * MT);
    const int4*   ov = (const int4*)(otab + (2 * NO + o3) * MT);
    float4 w0 = wv[0], w1 = wv[1], w2 = wv[2], w3 = wv[3];
    int4   j0 = ov[0], j1 = ov[1], j2 = ov[2], j3 = ov[3];
    float a0 = 0.f, a1 = 0.f, a2 = 0.f;
#define TAP3(J, W) { const float* v = (const float*)(base + (size_t)(unsigned)(J)); \
                     a0 += (W) * v[0]; a1 += (W) * v[1]; a2 += (W) * v[2]; }
    TAP3(j0.x, w0.x) TAP3(j0.y, w0.y) TAP3(j0.z, w0.z) TAP3(j0.w, w0.w)
    TAP3(j1.x, w1.x) TAP3(j1.y, w1.y) TAP3(j1.z, w1.z) TAP3(j1.w, w1.w)
    TAP3(j2.x, w2.x) TAP3(j2.y, w2.y) TAP3(j2.z, w2.z) TAP3(j2.w, w2.w)
    TAP3(j3.x, w3.x) TAP3(j3.y, w3.y) TAP3(j3.z, w3.z) TAP3(j3.w, w3.w)
#undef TAP3
    out[(size_t)idx * 3 + 0] = a0;
    out[(size_t)idx * 3 + 1] = a1;
    out[(size_t)idx * 3 + 2] = a2;
}

// ---------------------------------------------------------------------------
// FALLBACK (round-1, known-correct) fused pass A + pass B — used only if
// ws_size is too small for the intermediates.
// ---------------------------------------------------------------------------
__global__ __launch_bounds__(256) void k_passA(
        const float* __restrict__ img, const float* __restrict__ wtab,
        const int* __restrict__ wstart, float* __restrict__ S) {
    __shared__ float rows[CH * NI * NC];
    __shared__ float T[CH * NO * NC];
    __shared__ float acc[NO * NO * NC];
    __shared__ float w2[NO * MT], w3[NO * MT];
    __shared__ int   s2[NO], s3[NO];
    int t = threadIdx.x;
    int blk = blockIdx.x;
    const float* src = img + (size_t)blk * (NI * NI * NC);

    for (int k = t; k < NO * MT; k += 256) {
        w2[k] = wtab[NO * MT + k];
        w3[k] = wtab[2 * NO * MT + k];
    }
    for (int k = t; k < NO; k += 256) { s2[k] = wstart[NO + k]; s3[k] = wstart[2 * NO + k]; }
    for (int k = t; k < NO * NO * NC; k += 256) acc[k] = 0.f;
    __syncthreads();

    for (int chunk = 0; chunk < NI / CH; ++chunk) {
        const float4* csrc = (const float4*)(src + (size_t)chunk * CH * NI * NC);
        for (int k = t; k < CH * NI * NC / 4; k += 256)
            ((float4*)rows)[k] = csrc[k];
        __syncthreads();

        for (int task = t; task < CH * NO; task += 256) {
            int ch = task / NO, o3 = task % NO;
            int st = s3[o3];
            const float* rp = rows + ch * NI * NC;
            float a0 = 0.f, a1 = 0.f, a2 = 0.f;
            #pragma unroll
            for (int k = 0; k < MT; ++k) {
                int j = st + k; j = (j < NI) ? j : (NI - 1);
                float w = w3[o3 * MT + k];
                a0 += w * rp[j * 3 + 0];
                a1 += w * rp[j * 3 + 1];
                a2 += w * rp[j * 3 + 2];
            }
            T[task * NC + 0] = a0;
            T[task * NC + 1] = a1;
            T[task * NC + 2] = a2;
        }
        __syncthreads();

        int i2base = chunk * CH;
        for (int task = t; task < NO * NO; task += 256) {
            int o2 = task / NO, o3 = task % NO;
            int st = s2[o2];
            int k0 = i2base - st;        k0 = (k0 > 0) ? k0 : 0;
            int k1 = i2base + CH - st;   k1 = (k1 < MT) ? k1 : MT;
            if (k1 > k0) {
                float a0 = 0.f, a1 = 0.f, a2 = 0.f;
                for (int k = k0; k < k1; ++k) {
                    float w = w2[o2 * MT + k];
                    int ch = st + k - i2base;
                    a0 += w * T[(ch * NO + o3) * NC + 0];
                    a1 += w * T[(ch * NO + o3) * NC + 1];
                    a2 += w * T[(ch * NO + o3) * NC + 2];
                }
                acc[task * NC + 0] += a0;
                acc[task * NC + 1] += a1;
                acc[task * NC + 2] += a2;
            }
        }
        __syncthreads();
    }

    float* Sp = S + (size_t)blk * (NO * NO * NC);
    for (int k = t; k < NO * NO * NC; k += 256) Sp[k] = acc[k];
}

__global__ __launch_bounds__(256) void k_passB(
        const float* __restrict__ S, const float* __restrict__ wtab,
        const int* __restrict__ wstart, float* __restrict__ out) {
    int blk = blockIdx.x;
    int b = blk / NO, o1 = blk % NO;
    __shared__ float w1[MT];
    __shared__ int s1v;
    if (threadIdx.x < MT) w1[threadIdx.x] = wtab[o1 * MT + threadIdx.x];
    if (threadIdx.x == 0) s1v = wstart[o1];
    __syncthreads();
    const float* Sb = S + (size_t)b * NI * (NO * NO * NC);
    float* ob = out + (size_t)blk * (NO * NO * NC);
    int st = s1v;
    for (int e = threadIdx.x; e < NO * NO * NC; e += 256) {
        float a = 0.f;
        #pragma unroll
        for (int k = 0; k < MT; ++k) {
            int i1 = st + k; i1 = (i1 < NI) ? i1 : (NI - 1);
            a += w1[k] * Sb[(size_t)i1 * (NO * NO * NC) + e];
        }
        ob[e] = a;
    }
}

// ---------------------------------------------------------------------------
extern "C" void kernel_launch(void* const* d_in, const int* in_sizes, int n_in,
                              void* d_out, int out_size, void* d_ws, size_t ws_size,
                              hipStream_t stream) {
    (void)in_sizes; (void)n_in; (void)out_size;
    const float* img  = (const float*)d_in[0];
    const float* kern = (const float*)d_in[1];
    float* out = (float*)d_out;

    char* ws = (char*)d_ws;
    float* wtab   = (float*)ws;                       // 3*43*16 f  @ 0
    int*   wstart = (int*)(ws + 8256);                // 3*43 i32   @ 8256
    int*   otab   = (int*)(ws + 9216);                // 3*43*16 i32@ 9216

    const size_t TAB = 32768;
    const size_t A1_BYTES = A1_ELEMS * sizeof(float);            // 52.8 MB
    const size_t A2_BYTES = A2_ELEMS * sizeof(float);            // 14.2 MB

    k_setup<<<1, 256, 0, stream>>>(kern, wtab, wstart, otab);

    if (ws_size >= TAB + A1_BYTES + A2_BYTES) {
        float* A1 = (float*)(ws + TAB);
        float* A2 = (float*)(ws + TAB + A1_BYTES);
        int p1_blocks = (int)((size_t)NB * NI * NO * ROW4 / 256);          // 12900 exact
        k_c2<<<p1_blocks, 256, 0, stream>>>(img, wtab, otab, A1);
        int p2_blocks = (int)(((size_t)NB * NO * NO * ROW4 + 255) / 256);  // 3466
        k_c1<<<p2_blocks, 256, 0, stream>>>(A1, wtab, otab, A2);
        int p3_blocks = (int)(((size_t)NB * NO * NO * NO + 255) / 256);    // 1243
        k_c3<<<p3_blocks, 256, 0, stream>>>(A2, wtab, otab, out);
    } else {
        float* S = (float*)(ws + TAB);
        k_passA<<<NB * NI, 256, 0, stream>>>(img, wtab, wstart, S);
        k_passB<<<NB * NO, 256, 0, stream>>>(S, wtab, wstart, out);
    }
}